// Round 12
// baseline (412.792 us; speedup 1.0000x reference)
//
#include <hip/hip_runtime.h>

typedef float v2f __attribute__((ext_vector_type(2)));

// ---------------- compile-time PGA(3,0,1) tables ----------------
namespace pga {
// blade order: (),e0,e1,e2,e3,e01,e02,e03,e12,e13,e23,e012,e013,e023,e123,e0123
constexpr int MASKA[16] = {0,1,2,4,8,3,5,9,6,10,12,7,11,13,14,15};
constexpr int IMASK[16] = {0,1,2,5,3,6,8,11,4,7,9,12,10,13,14,15}; // mask -> idx
constexpr int GR[16]    = {0,1,1,1,1,2,2,2,2,2,2,3,3,3,3,4};

constexpr int osign(int a, int b){ // parity of cross inversions of sorted(a)++sorted(b)
  int c = 0;
  for (int j = 0; j < 4; ++j) if ((b>>j)&1)
    for (int i = j+1; i < 4; ++i) if ((a>>i)&1) ++c;
  return (c&1) ? -1 : 1;
}

struct Tab {
  float gpc[16][16]; int gpk[16][16];
  float jnc[16][16]; int jnk[16][16];
};

constexpr Tab build(){
  Tab t{};
  for (int i = 0; i < 16; ++i) for (int j = 0; j < 16; ++j) {
    const int ma = MASKA[i], mb = MASKA[j];
    // geometric product (e0^2 = 0)
    if (ma & mb & 1) { t.gpc[i][j] = 0.0f; t.gpk[i][j] = 0; }
    else { t.gpk[i][j] = IMASK[ma^mb]; t.gpc[i][j] = (float)osign(ma, mb); }
    // join(x,y) = undual(dual(x) ^ dual(y)), right-complement dual
    const int ua = 15^ma, ub = 15^mb;
    if (ua & ub) { t.jnc[i][j] = 0.0f; t.jnk[i][j] = 0; }
    else {
      const int sa = osign(ma, ua), sb = osign(mb, ub);
      const int m  = ua | ub;
      const int tt = osign(ua, ub);
      const int r  = 15^m;
      const int sr = osign(r, m);
      t.jnk[i][j] = IMASK[r];
      t.jnc[i][j] = (float)(sa*sb*tt*sr);
    }
  }
  return t;
}
constexpr Tab TAB = build();
// (src, e0-blade) pairs; src = blade \ e0, always earlier in order
constexpr int PS[8] = {0,2,3,4,8,9,10,14};
constexpr int PE[8] = {1,5,6,7,11,12,13,15};
} // namespace pga

// ---------------- helpers ----------------
__device__ __forceinline__ float sel4(float a, float b, float c, float d, int k){
  float lo = (k & 1) ? b : a;
  float hi = (k & 1) ? d : c;
  return (k & 2) ? hi : lo;
}
// cross-quad butterfly adds via DPP quad_perm (VALU pipe, no LDS traffic)
__device__ __forceinline__ float xadd1(float v){
  return v + __int_as_float(__builtin_amdgcn_update_dpp(0, __float_as_int(v), 0xB1, 0xF, 0xF, false)); // [1,0,3,2]
}
__device__ __forceinline__ float xadd2(float v){
  return v + __int_as_float(__builtin_amdgcn_update_dpp(0, __float_as_int(v), 0x4E, 0xF, 0xF, false)); // [2,3,0,1]
}

#define NP 8
#define XS_PITCH 584      // per-position floats: 16 rows x 36 + 8 pad (584%32=8 de-phases positions for Phase-B writes)
#define HS_BASE  4672     // NP * XS_PITCH
#define HS_OPITCH 17      // odd pitch: 16 lanes x stride 17 -> 16 distinct banks
#define HS_PPITCH 1092    // 64 rows x 17 + 4 (bank de-phase across positions)

template <int Q0>
__device__ __forceinline__ void equi2_half(const float* __restrict__ yb,
                                           const v2f (&WC)[4][9], v2f (&acc)[8]) {
  #pragma unroll
  for (int q = Q0; q < Q0 + 4; ++q) {
    const int s = pga::PS[q], e = pga::PE[q];
    const int js = s - (Q0/4)*8, je = e - (Q0/4)*8;
    float4 s0 = *(const float4*)(yb + s*36);
    float4 s1 = *(const float4*)(yb + s*36 + 4);
    float4 t0 = *(const float4*)(yb + e*36);
    float4 t1 = *(const float4*)(yb + e*36 + 4);
    v2f ys2[4] = { {s0.x,s0.y},{s0.z,s0.w},{s1.x,s1.y},{s1.z,s1.w} };
    v2f ye2[4] = { {t0.x,t0.y},{t0.z,t0.w},{t1.x,t1.y},{t1.z,t1.w} };
    const int gs = pga::GR[s], ge = pga::GR[e];
    #pragma unroll
    for (int cp = 0; cp < 4; ++cp) {
      acc[js] += WC[cp][gs]    * ys2[cp];
      acc[je] += WC[cp][ge]    * ye2[cp];
      acc[je] += WC[cp][4+ge]  * ys2[cp];   // e0-wedge map, sign +1
    }
  }
}

__attribute__((amdgpu_waves_per_eu(2, 3)))
__launch_bounds__(256)
__global__ void pga_fused(const float* __restrict__ x, const float* __restrict__ refmv,
                          const float* __restrict__ Wb, const float* __restrict__ Wo,
                          float* __restrict__ out)
{
  __shared__ float lds[13408]; // 53632 B (rounds to 53760): xs/ys overlay [0,4672) + hs [4672,13408)
  const int tid = threadIdx.x;
  const long long pos0 = (long long)blockIdx.x * NP;

  // ---- hoisted scalar: refmv e123 component for this thread's Phase-B position
  const float sref = refmv[(pos0 + ((tid >> 4) & 7))*16 + 14];

  // ---- Phase A weights in registers: thread (o = tid>>2, cb = tid&3), c in [8cb, 8cb+8)
  const int oA = tid >> 2, cbA = tid & 3;
  v2f WA[4][9];
  {
    const float* wb = Wb + (size_t)(oA*32 + cbA*8)*9;
    #pragma unroll
    for (int cp = 0; cp < 4; ++cp)
      #pragma unroll
      for (int w = 0; w < 9; ++w)
        WA[cp][w] = (v2f){ wb[(2*cp)*9 + w], wb[(2*cp+1)*9 + w] };
  }

  // ---- stage x -> LDS transposed xs[p][a][36] (conflict-free layout)
  {
    const float4* xg = (const float4*)(x + pos0*512);
    #pragma unroll
    for (int r = 0; r < 4; ++r) {
      int idx = tid + 256*r;           // idx = p*128 + c*4 + aq
      float4 g = xg[idx];
      int p = idx >> 7, c = (idx >> 2) & 31, aq = idx & 3;
      float* b = &lds[p*XS_PITCH + c];
      b[(aq*4+0)*36] = g.x;
      b[(aq*4+1)*36] = g.y;
      b[(aq*4+2)*36] = g.z;
      b[(aq*4+3)*36] = g.w;
    }
  }
  __syncthreads();

  // ---- Phase A: equi_linear(x, W_bil) -> hs (unroll 2: two independent pos chains)
  #pragma unroll 2
  for (int p = 0; p < NP; ++p) {
    const float* xb = &lds[p*XS_PITCH + cbA*8];
    v2f acc[16];
    #pragma unroll
    for (int a = 0; a < 16; ++a) acc[a] = (v2f){0.f, 0.f};
    #pragma unroll
    for (int q = 0; q < 8; ++q) {
      const int s = pga::PS[q], e = pga::PE[q];
      float4 s0 = *(const float4*)(xb + s*36);
      float4 s1 = *(const float4*)(xb + s*36 + 4);
      float4 t0 = *(const float4*)(xb + e*36);
      float4 t1 = *(const float4*)(xb + e*36 + 4);
      v2f xs2[4] = { {s0.x,s0.y},{s0.z,s0.w},{s1.x,s1.y},{s1.z,s1.w} };
      v2f xe2[4] = { {t0.x,t0.y},{t0.z,t0.w},{t1.x,t1.y},{t1.z,t1.w} };
      const int gs = pga::GR[s], ge = pga::GR[e];
      #pragma unroll
      for (int cp = 0; cp < 4; ++cp) {
        acc[s] += WA[cp][gs]   * xs2[cp];
        acc[e] += WA[cp][ge]   * xe2[cp];
        acc[e] += WA[cp][4+ge] * xs2[cp];
      }
    }
    float h[16];
    #pragma unroll
    for (int a = 0; a < 16; ++a) h[a] = xadd2(xadd1(acc[a].x + acc[a].y));
    float4 v;
    v.x = sel4(h[0], h[4], h[8],  h[12], cbA);
    v.y = sel4(h[1], h[5], h[9],  h[13], cbA);
    v.z = sel4(h[2], h[6], h[10], h[14], cbA);
    v.w = sel4(h[3], h[7], h[11], h[15], cbA);
    *(float4*)&lds[HS_BASE + p*HS_PPITCH + oA*HS_OPITCH + cbA*4] = v;
  }
  __syncthreads();

  // ---- Phase C weights hoisted BEFORE Phase B: HBM/L2 latency hides under B's compute.
  //      (WA is dead by now, so no weight-array liveness overlap.)
  const int ahC = tid >> 7, oC = (tid >> 2) & 31, cbC = tid & 3;
  v2f WC[4][9];
  {
    const float* wo = Wo + (size_t)(oC*32 + cbC*8)*9;
    #pragma unroll
    for (int cp = 0; cp < 4; ++cp)
      #pragma unroll
      for (int w = 0; w < 9; ++w)
        WC[cp][w] = (v2f){ wo[(2*cp)*9 + w], wo[(2*cp+1)*9 + w] };
  }

  // ---- Phase B: per-channel GP / JOIN (wave-uniform half)
  {
    const int half = tid >> 7, pb = (tid >> 4) & 7, cc = tid & 15;
    const float* r0 = &lds[HS_BASE + pb*HS_PPITCH + (half*32 + cc)*HS_OPITCH];
    const float* r1 = r0 + 16*HS_OPITCH;
    float L[16], R[16];
    #pragma unroll
    for (int k = 0; k < 4; ++k) {
      *(float4*)&L[k*4] = *(const float4*)(r0 + k*4);
      *(float4*)&R[k*4] = *(const float4*)(r1 + k*4);
    }
    float acc[16];
    #pragma unroll
    for (int k = 0; k < 16; ++k) acc[k] = 0.f;
    if (half == 0) {
      #pragma unroll
      for (int i = 0; i < 16; ++i)
        #pragma unroll
        for (int j = 0; j < 16; ++j)
          if (pga::TAB.gpc[i][j] != 0.0f)
            acc[pga::TAB.gpk[i][j]] = fmaf(pga::TAB.gpc[i][j]*L[i], R[j], acc[pga::TAB.gpk[i][j]]);
    } else {
      #pragma unroll
      for (int i = 0; i < 16; ++i)
        #pragma unroll
        for (int j = 0; j < 16; ++j)
          if (pga::TAB.jnc[i][j] != 0.0f)
            acc[pga::TAB.jnk[i][j]] = fmaf(pga::TAB.jnc[i][j]*L[i], R[j], acc[pga::TAB.jnk[i][j]]);
      #pragma unroll
      for (int k = 0; k < 16; ++k) acc[k] *= sref;
    }
    // write y transposed into xs region (x is dead): ys[p][a][col], col = half*16+cc
    // XS_PITCH=584 (%32==8) de-phases pb across banks: 4-way conflict -> 2-way (free)
    float* yb = &lds[pb*XS_PITCH + (half*16 + cc)];
    #pragma unroll
    for (int a = 0; a < 16; ++a) yb[a*36] = acc[a];
  }
  __syncthreads();

  // ---- Phase C: equi_linear(y, W_out) -> out (unroll 2)
  #pragma unroll 2
  for (int p = 0; p < NP; ++p) {
    const float* yb = &lds[p*XS_PITCH + cbC*8];
    v2f acc[8];
    #pragma unroll
    for (int j = 0; j < 8; ++j) acc[j] = (v2f){0.f, 0.f};
    if (ahC == 0) equi2_half<0>(yb, WC, acc);
    else          equi2_half<4>(yb, WC, acc);
    float f[8];
    #pragma unroll
    for (int j = 0; j < 8; ++j) f[j] = xadd2(xadd1(acc[j].x + acc[j].y));
    float2 st;
    st.x = sel4(f[0], f[2], f[4], f[6], cbC);
    st.y = sel4(f[1], f[3], f[5], f[7], cbC);
    *(float2*)&out[(pos0 + p)*512 + oC*16 + ahC*8 + cbC*2] = st;
  }
}

extern "C" void kernel_launch(void* const* d_in, const int* in_sizes, int n_in,
                              void* d_out, int out_size, void* d_ws, size_t ws_size,
                              hipStream_t stream) {
  const float* x  = (const float*)d_in[0];
  const float* rm = (const float*)d_in[1];
  const float* wb = (const float*)d_in[2];
  const float* wo = (const float*)d_in[3];
  float* out = (float*)d_out;
  const int P = in_sizes[0] / 512;   // B*S positions
  const int blocks = P / NP;         // 8192 for the bench shape
  pga_fused<<<blocks, 256, 0, stream>>>(x, rm, wb, wo, out);
}

// Round 13
// 389.405 us; speedup vs baseline: 1.0601x; 1.0601x over previous
//
#include <hip/hip_runtime.h>

typedef float v2f __attribute__((ext_vector_type(2)));

// ---------------- compile-time PGA(3,0,1) tables ----------------
namespace pga {
// blade order: (),e0,e1,e2,e3,e01,e02,e03,e12,e13,e23,e012,e013,e023,e123,e0123
constexpr int MASKA[16] = {0,1,2,4,8,3,5,9,6,10,12,7,11,13,14,15};
constexpr int IMASK[16] = {0,1,2,5,3,6,8,11,4,7,9,12,10,13,14,15}; // mask -> idx
constexpr int GR[16]    = {0,1,1,1,1,2,2,2,2,2,2,3,3,3,3,4};

constexpr int osign(int a, int b){ // parity of cross inversions of sorted(a)++sorted(b)
  int c = 0;
  for (int j = 0; j < 4; ++j) if ((b>>j)&1)
    for (int i = j+1; i < 4; ++i) if ((a>>i)&1) ++c;
  return (c&1) ? -1 : 1;
}

struct Tab {
  float gpc[16][16]; int gpk[16][16];
  float jnc[16][16]; int jnk[16][16];
};

constexpr Tab build(){
  Tab t{};
  for (int i = 0; i < 16; ++i) for (int j = 0; j < 16; ++j) {
    const int ma = MASKA[i], mb = MASKA[j];
    // geometric product (e0^2 = 0)
    if (ma & mb & 1) { t.gpc[i][j] = 0.0f; t.gpk[i][j] = 0; }
    else { t.gpk[i][j] = IMASK[ma^mb]; t.gpc[i][j] = (float)osign(ma, mb); }
    // join(x,y) = undual(dual(x) ^ dual(y)), right-complement dual
    const int ua = 15^ma, ub = 15^mb;
    if (ua & ub) { t.jnc[i][j] = 0.0f; t.jnk[i][j] = 0; }
    else {
      const int sa = osign(ma, ua), sb = osign(mb, ub);
      const int m  = ua | ub;
      const int tt = osign(ua, ub);
      const int r  = 15^m;
      const int sr = osign(r, m);
      t.jnk[i][j] = IMASK[r];
      t.jnc[i][j] = (float)(sa*sb*tt*sr);
    }
  }
  return t;
}
constexpr Tab TAB = build();
// (src, e0-blade) pairs; src = blade \ e0, always earlier in order
constexpr int PS[8] = {0,2,3,4,8,9,10,14};
constexpr int PE[8] = {1,5,6,7,11,12,13,15};
} // namespace pga

// ---------------- helpers ----------------
__device__ __forceinline__ float sel4(float a, float b, float c, float d, int k){
  float lo = (k & 1) ? b : a;
  float hi = (k & 1) ? d : c;
  return (k & 2) ? hi : lo;
}
// cross-quad butterfly adds via DPP quad_perm (VALU pipe, no LDS traffic)
__device__ __forceinline__ float xadd1(float v){
  return v + __int_as_float(__builtin_amdgcn_update_dpp(0, __float_as_int(v), 0xB1, 0xF, 0xF, false)); // [1,0,3,2]
}
__device__ __forceinline__ float xadd2(float v){
  return v + __int_as_float(__builtin_amdgcn_update_dpp(0, __float_as_int(v), 0x4E, 0xF, 0xF, false)); // [2,3,0,1]
}

#define NP 8
#define XS_PITCH 584      // per-position floats: 16 rows x 36 + 8 pad (584%32=8 de-phases positions for Phase-B writes)
#define HS_BASE  4672     // NP * XS_PITCH
#define HS_OPITCH 17      // odd pitch: 16 lanes x stride 17 -> 16 distinct banks
#define HS_PPITCH 1092    // 64 rows x 17 + 4 (bank de-phase across positions)

template <int Q0>
__device__ __forceinline__ void equi2_half(const float* __restrict__ yb,
                                           const v2f (&WC)[4][9], v2f (&acc)[8]) {
  #pragma unroll
  for (int q = Q0; q < Q0 + 4; ++q) {
    const int s = pga::PS[q], e = pga::PE[q];
    const int js = s - (Q0/4)*8, je = e - (Q0/4)*8;
    float4 s0 = *(const float4*)(yb + s*36);
    float4 s1 = *(const float4*)(yb + s*36 + 4);
    float4 t0 = *(const float4*)(yb + e*36);
    float4 t1 = *(const float4*)(yb + e*36 + 4);
    v2f ys2[4] = { {s0.x,s0.y},{s0.z,s0.w},{s1.x,s1.y},{s1.z,s1.w} };
    v2f ye2[4] = { {t0.x,t0.y},{t0.z,t0.w},{t1.x,t1.y},{t1.z,t1.w} };
    const int gs = pga::GR[s], ge = pga::GR[e];
    #pragma unroll
    for (int cp = 0; cp < 4; ++cp) {
      acc[js] += WC[cp][gs]    * ys2[cp];
      acc[je] += WC[cp][ge]    * ye2[cp];
      acc[je] += WC[cp][4+ge]  * ys2[cp];   // e0-wedge map, sign +1
    }
  }
}

__attribute__((amdgpu_waves_per_eu(2, 3)))
__launch_bounds__(256)
__global__ void pga_fused(const float* __restrict__ x, const float* __restrict__ refmv,
                          const float* __restrict__ Wb, const float* __restrict__ Wo,
                          float* __restrict__ out)
{
  __shared__ float lds[13408]; // 53632 B (rounds to 53760): xs/ys overlay [0,4672) + hs [4672,13408)
  const int tid = threadIdx.x;
  const long long pos0 = (long long)blockIdx.x * NP;

  // ---- hoisted scalar: refmv e123 component for this thread's Phase-B position
  const float sref = refmv[(pos0 + ((tid >> 4) & 7))*16 + 14];

  // ---- Phase A weights in registers: thread (o = tid>>2, cb = tid&3), c in [8cb, 8cb+8)
  const int oA = tid >> 2, cbA = tid & 3;
  v2f WA[4][9];
  {
    const float* wb = Wb + (size_t)(oA*32 + cbA*8)*9;
    #pragma unroll
    for (int cp = 0; cp < 4; ++cp)
      #pragma unroll
      for (int w = 0; w < 9; ++w)
        WA[cp][w] = (v2f){ wb[(2*cp)*9 + w], wb[(2*cp+1)*9 + w] };
  }

  // ---- stage x -> LDS transposed xs[p][a][36] (conflict-free layout)
  {
    const float4* xg = (const float4*)(x + pos0*512);
    #pragma unroll
    for (int r = 0; r < 4; ++r) {
      int idx = tid + 256*r;           // idx = p*128 + c*4 + aq
      float4 g = xg[idx];
      int p = idx >> 7, c = (idx >> 2) & 31, aq = idx & 3;
      float* b = &lds[p*XS_PITCH + c];
      b[(aq*4+0)*36] = g.x;
      b[(aq*4+1)*36] = g.y;
      b[(aq*4+2)*36] = g.z;
      b[(aq*4+3)*36] = g.w;
    }
  }
  __syncthreads();

  // ---- Phase A: equi_linear(x, W_bil) -> hs (unroll 2: two independent pos chains)
  #pragma unroll 2
  for (int p = 0; p < NP; ++p) {
    const float* xb = &lds[p*XS_PITCH + cbA*8];
    v2f acc[16];
    #pragma unroll
    for (int a = 0; a < 16; ++a) acc[a] = (v2f){0.f, 0.f};
    #pragma unroll
    for (int q = 0; q < 8; ++q) {
      const int s = pga::PS[q], e = pga::PE[q];
      float4 s0 = *(const float4*)(xb + s*36);
      float4 s1 = *(const float4*)(xb + s*36 + 4);
      float4 t0 = *(const float4*)(xb + e*36);
      float4 t1 = *(const float4*)(xb + e*36 + 4);
      v2f xs2[4] = { {s0.x,s0.y},{s0.z,s0.w},{s1.x,s1.y},{s1.z,s1.w} };
      v2f xe2[4] = { {t0.x,t0.y},{t0.z,t0.w},{t1.x,t1.y},{t1.z,t1.w} };
      const int gs = pga::GR[s], ge = pga::GR[e];
      #pragma unroll
      for (int cp = 0; cp < 4; ++cp) {
        acc[s] += WA[cp][gs]   * xs2[cp];
        acc[e] += WA[cp][ge]   * xe2[cp];
        acc[e] += WA[cp][4+ge] * xs2[cp];
      }
    }
    float h[16];
    #pragma unroll
    for (int a = 0; a < 16; ++a) h[a] = xadd2(xadd1(acc[a].x + acc[a].y));
    float4 v;
    v.x = sel4(h[0], h[4], h[8],  h[12], cbA);
    v.y = sel4(h[1], h[5], h[9],  h[13], cbA);
    v.z = sel4(h[2], h[6], h[10], h[14], cbA);
    v.w = sel4(h[3], h[7], h[11], h[15], cbA);
    *(float4*)&lds[HS_BASE + p*HS_PPITCH + oA*HS_OPITCH + cbA*4] = v;
  }
  __syncthreads();

  // ---- Phase B: per-channel GP / JOIN (wave-uniform half)
  {
    const int half = tid >> 7, pb = (tid >> 4) & 7, cc = tid & 15;
    const float* r0 = &lds[HS_BASE + pb*HS_PPITCH + (half*32 + cc)*HS_OPITCH];
    const float* r1 = r0 + 16*HS_OPITCH;
    float L[16], R[16];
    #pragma unroll
    for (int k = 0; k < 4; ++k) {
      *(float4*)&L[k*4] = *(const float4*)(r0 + k*4);
      *(float4*)&R[k*4] = *(const float4*)(r1 + k*4);
    }
    float acc[16];
    #pragma unroll
    for (int k = 0; k < 16; ++k) acc[k] = 0.f;
    if (half == 0) {
      #pragma unroll
      for (int i = 0; i < 16; ++i)
        #pragma unroll
        for (int j = 0; j < 16; ++j)
          if (pga::TAB.gpc[i][j] != 0.0f)
            acc[pga::TAB.gpk[i][j]] = fmaf(pga::TAB.gpc[i][j]*L[i], R[j], acc[pga::TAB.gpk[i][j]]);
    } else {
      #pragma unroll
      for (int i = 0; i < 16; ++i)
        #pragma unroll
        for (int j = 0; j < 16; ++j)
          if (pga::TAB.jnc[i][j] != 0.0f)
            acc[pga::TAB.jnk[i][j]] = fmaf(pga::TAB.jnc[i][j]*L[i], R[j], acc[pga::TAB.jnk[i][j]]);
      #pragma unroll
      for (int k = 0; k < 16; ++k) acc[k] *= sref;
    }
    // write y transposed into xs region (x is dead): ys[p][a][col], col = half*16+cc
    // XS_PITCH=584 (%32==8) de-phases pb across banks: 4-way conflict -> 2-way (free)
    float* yb = &lds[pb*XS_PITCH + (half*16 + cc)];
    #pragma unroll
    for (int a = 0; a < 16; ++a) yb[a*36] = acc[a];
  }

  // ---- Phase C weights (loaded after Phase B so WA/L/R/acc liveness never overlaps WC:
  //      r12 measured the hoisted version at 128 VGPR -> occupancy collapse)
  const int ahC = tid >> 7, oC = (tid >> 2) & 31, cbC = tid & 3;
  v2f WC[4][9];
  {
    const float* wo = Wo + (size_t)(oC*32 + cbC*8)*9;
    #pragma unroll
    for (int cp = 0; cp < 4; ++cp)
      #pragma unroll
      for (int w = 0; w < 9; ++w)
        WC[cp][w] = (v2f){ wo[(2*cp)*9 + w], wo[(2*cp+1)*9 + w] };
  }
  __syncthreads();

  // ---- Phase C: equi_linear(y, W_out) -> out (unroll 2)
  #pragma unroll 2
  for (int p = 0; p < NP; ++p) {
    const float* yb = &lds[p*XS_PITCH + cbC*8];
    v2f acc[8];
    #pragma unroll
    for (int j = 0; j < 8; ++j) acc[j] = (v2f){0.f, 0.f};
    if (ahC == 0) equi2_half<0>(yb, WC, acc);
    else          equi2_half<4>(yb, WC, acc);
    float f[8];
    #pragma unroll
    for (int j = 0; j < 8; ++j) f[j] = xadd2(xadd1(acc[j].x + acc[j].y));
    float2 st;
    st.x = sel4(f[0], f[2], f[4], f[6], cbC);
    st.y = sel4(f[1], f[3], f[5], f[7], cbC);
    *(float2*)&out[(pos0 + p)*512 + oC*16 + ahC*8 + cbC*2] = st;
  }
}

extern "C" void kernel_launch(void* const* d_in, const int* in_sizes, int n_in,
                              void* d_out, int out_size, void* d_ws, size_t ws_size,
                              hipStream_t stream) {
  const float* x  = (const float*)d_in[0];
  const float* rm = (const float*)d_in[1];
  const float* wb = (const float*)d_in[2];
  const float* wo = (const float*)d_in[3];
  float* out = (float*)d_out;
  const int P = in_sizes[0] / 512;   // B*S positions
  const int blocks = P / NP;         // 8192 for the bench shape
  pga_fused<<<blocks, 256, 0, stream>>>(x, rm, wb, wo, out);
}

// Round 15
// 386.859 us; speedup vs baseline: 1.0670x; 1.0066x over previous
//
#include <hip/hip_runtime.h>

typedef float v2f __attribute__((ext_vector_type(2)));

// ---------------- compile-time PGA(3,0,1) tables ----------------
namespace pga {
// blade order: (),e0,e1,e2,e3,e01,e02,e03,e12,e13,e23,e012,e013,e023,e123,e0123
constexpr int MASKA[16] = {0,1,2,4,8,3,5,9,6,10,12,7,11,13,14,15};
constexpr int IMASK[16] = {0,1,2,5,3,6,8,11,4,7,9,12,10,13,14,15}; // mask -> idx
constexpr int GR[16]    = {0,1,1,1,1,2,2,2,2,2,2,3,3,3,3,4};

constexpr int osign(int a, int b){ // parity of cross inversions of sorted(a)++sorted(b)
  int c = 0;
  for (int j = 0; j < 4; ++j) if ((b>>j)&1)
    for (int i = j+1; i < 4; ++i) if ((a>>i)&1) ++c;
  return (c&1) ? -1 : 1;
}

struct Tab {
  float gpc[16][16]; int gpk[16][16];
  float jnc[16][16]; int jnk[16][16];
};

constexpr Tab build(){
  Tab t{};
  for (int i = 0; i < 16; ++i) for (int j = 0; j < 16; ++j) {
    const int ma = MASKA[i], mb = MASKA[j];
    // geometric product (e0^2 = 0)
    if (ma & mb & 1) { t.gpc[i][j] = 0.0f; t.gpk[i][j] = 0; }
    else { t.gpk[i][j] = IMASK[ma^mb]; t.gpc[i][j] = (float)osign(ma, mb); }
    // join(x,y) = undual(dual(x) ^ dual(y)), right-complement dual
    const int ua = 15^ma, ub = 15^mb;
    if (ua & ub) { t.jnc[i][j] = 0.0f; t.jnk[i][j] = 0; }
    else {
      const int sa = osign(ma, ua), sb = osign(mb, ub);
      const int m  = ua | ub;
      const int tt = osign(ua, ub);
      const int r  = 15^m;
      const int sr = osign(r, m);
      t.jnk[i][j] = IMASK[r];
      t.jnc[i][j] = (float)(sa*sb*tt*sr);
    }
  }
  return t;
}
constexpr Tab TAB = build();
// (src, e0-blade) pairs; src = blade \ e0, always earlier in order
constexpr int PS[8] = {0,2,3,4,8,9,10,14};
constexpr int PE[8] = {1,5,6,7,11,12,13,15};
} // namespace pga

// ---------------- helpers ----------------
__device__ __forceinline__ float sel4(float a, float b, float c, float d, int k){
  float lo = (k & 1) ? b : a;
  float hi = (k & 1) ? d : c;
  return (k & 2) ? hi : lo;
}
// cross-quad butterfly adds via DPP quad_perm (VALU pipe, no LDS traffic).
// NOTE: keep the builtin (v_mov_b32_dpp + v_add_f32). A fused v_add_f32_dpp via
// inline asm hits the VALU->DPP hazard (needs s_nop the compiler won't insert
// around asm) -- r14 failed correctness exactly this way, and a correct fused
// version costs the same 2 issue slots. This form is hazard-free by construction.
__device__ __forceinline__ float xadd1(float v){
  return v + __int_as_float(__builtin_amdgcn_update_dpp(0, __float_as_int(v), 0xB1, 0xF, 0xF, false)); // [1,0,3,2]
}
__device__ __forceinline__ float xadd2(float v){
  return v + __int_as_float(__builtin_amdgcn_update_dpp(0, __float_as_int(v), 0x4E, 0xF, 0xF, false)); // [2,3,0,1]
}

#define NP 8
#define XS_PITCH 576      // per-position floats: 16 rows x 36 (32 cols + pad)
#define HS_BASE  4608
#define HS_OPITCH 17      // odd pitch: 16 lanes x stride 17 -> 16 distinct banks
#define HS_PPITCH 1092    // 64 rows x 17 + 4 (bank de-phase across positions)

template <int Q0>
__device__ __forceinline__ void equi2_half(const float* __restrict__ yb,
                                           const v2f (&WC)[4][9], v2f (&acc)[8]) {
  #pragma unroll
  for (int q = Q0; q < Q0 + 4; ++q) {
    const int s = pga::PS[q], e = pga::PE[q];
    const int js = s - (Q0/4)*8, je = e - (Q0/4)*8;
    float4 s0 = *(const float4*)(yb + s*36);
    float4 s1 = *(const float4*)(yb + s*36 + 4);
    float4 t0 = *(const float4*)(yb + e*36);
    float4 t1 = *(const float4*)(yb + e*36 + 4);
    v2f ys2[4] = { {s0.x,s0.y},{s0.z,s0.w},{s1.x,s1.y},{s1.z,s1.w} };
    v2f ye2[4] = { {t0.x,t0.y},{t0.z,t0.w},{t1.x,t1.y},{t1.z,t1.w} };
    const int gs = pga::GR[s], ge = pga::GR[e];
    #pragma unroll
    for (int cp = 0; cp < 4; ++cp) {
      acc[js] += WC[cp][gs]    * ys2[cp];
      acc[je] += WC[cp][ge]    * ye2[cp];
      acc[je] += WC[cp][4+ge]  * ys2[cp];   // e0-wedge map, sign +1
    }
  }
}

__attribute__((amdgpu_waves_per_eu(2, 3)))
__launch_bounds__(256)
__global__ void pga_fused(const float* __restrict__ x, const float* __restrict__ refmv,
                          const float* __restrict__ Wb, const float* __restrict__ Wo,
                          float* __restrict__ out)
{
  __shared__ float lds[13344]; // 53376 B: xs/ys overlay [0,4608) + hs [4608,13344)
  const int tid = threadIdx.x;
  const long long pos0 = (long long)blockIdx.x * NP;

  // ---- Phase A weights in registers: thread (o = tid>>2, cb = tid&3), c in [8cb, 8cb+8)
  const int oA = tid >> 2, cbA = tid & 3;
  v2f WA[4][9];
  {
    const float* wb = Wb + (size_t)(oA*32 + cbA*8)*9;
    #pragma unroll
    for (int cp = 0; cp < 4; ++cp)
      #pragma unroll
      for (int w = 0; w < 9; ++w)
        WA[cp][w] = (v2f){ wb[(2*cp)*9 + w], wb[(2*cp+1)*9 + w] };
  }

  // ---- stage x -> LDS transposed xs[p][a][36] (conflict-free layout)
  {
    const float4* xg = (const float4*)(x + pos0*512);
    #pragma unroll
    for (int r = 0; r < 4; ++r) {
      int idx = tid + 256*r;           // idx = p*128 + c*4 + aq
      float4 g = xg[idx];
      int p = idx >> 7, c = (idx >> 2) & 31, aq = idx & 3;
      float* b = &lds[p*XS_PITCH + c];
      b[(aq*4+0)*36] = g.x;
      b[(aq*4+1)*36] = g.y;
      b[(aq*4+2)*36] = g.z;
      b[(aq*4+3)*36] = g.w;
    }
  }
  __syncthreads();

  // ---- Phase A: equi_linear(x, W_bil) -> hs (unroll 2: two independent pos chains)
  #pragma unroll 2
  for (int p = 0; p < NP; ++p) {
    const float* xb = &lds[p*XS_PITCH + cbA*8];
    v2f acc[16];
    #pragma unroll
    for (int a = 0; a < 16; ++a) acc[a] = (v2f){0.f, 0.f};
    #pragma unroll
    for (int q = 0; q < 8; ++q) {
      const int s = pga::PS[q], e = pga::PE[q];
      float4 s0 = *(const float4*)(xb + s*36);
      float4 s1 = *(const float4*)(xb + s*36 + 4);
      float4 t0 = *(const float4*)(xb + e*36);
      float4 t1 = *(const float4*)(xb + e*36 + 4);
      v2f xs2[4] = { {s0.x,s0.y},{s0.z,s0.w},{s1.x,s1.y},{s1.z,s1.w} };
      v2f xe2[4] = { {t0.x,t0.y},{t0.z,t0.w},{t1.x,t1.y},{t1.z,t1.w} };
      const int gs = pga::GR[s], ge = pga::GR[e];
      #pragma unroll
      for (int cp = 0; cp < 4; ++cp) {
        acc[s] += WA[cp][gs]   * xs2[cp];
        acc[e] += WA[cp][ge]   * xe2[cp];
        acc[e] += WA[cp][4+ge] * xs2[cp];
      }
    }
    float h[16];
    #pragma unroll
    for (int a = 0; a < 16; ++a) h[a] = xadd2(xadd1(acc[a].x + acc[a].y));
    float4 v;
    v.x = sel4(h[0], h[4], h[8],  h[12], cbA);
    v.y = sel4(h[1], h[5], h[9],  h[13], cbA);
    v.z = sel4(h[2], h[6], h[10], h[14], cbA);
    v.w = sel4(h[3], h[7], h[11], h[15], cbA);
    *(float4*)&lds[HS_BASE + p*HS_PPITCH + oA*HS_OPITCH + cbA*4] = v;
  }
  __syncthreads();

  // ---- Phase B: per-channel GP / JOIN (wave-uniform half)
  {
    const int half = tid >> 7, pb = (tid >> 4) & 7, cc = tid & 15;
    const float* r0 = &lds[HS_BASE + pb*HS_PPITCH + (half*32 + cc)*HS_OPITCH];
    const float* r1 = r0 + 16*HS_OPITCH;
    float L[16], R[16];
    #pragma unroll
    for (int k = 0; k < 4; ++k) {
      *(float4*)&L[k*4] = *(const float4*)(r0 + k*4);
      *(float4*)&R[k*4] = *(const float4*)(r1 + k*4);
    }
    float acc[16];
    #pragma unroll
    for (int k = 0; k < 16; ++k) acc[k] = 0.f;
    if (half == 0) {
      #pragma unroll
      for (int i = 0; i < 16; ++i)
        #pragma unroll
        for (int j = 0; j < 16; ++j)
          if (pga::TAB.gpc[i][j] != 0.0f)
            acc[pga::TAB.gpk[i][j]] = fmaf(pga::TAB.gpc[i][j]*L[i], R[j], acc[pga::TAB.gpk[i][j]]);
    } else {
      #pragma unroll
      for (int i = 0; i < 16; ++i)
        #pragma unroll
        for (int j = 0; j < 16; ++j)
          if (pga::TAB.jnc[i][j] != 0.0f)
            acc[pga::TAB.jnk[i][j]] = fmaf(pga::TAB.jnc[i][j]*L[i], R[j], acc[pga::TAB.jnk[i][j]]);
      const float s = refmv[(pos0 + pb)*16 + 14];
      #pragma unroll
      for (int k = 0; k < 16; ++k) acc[k] *= s;
    }
    // write y transposed into xs region (x is dead): ys[p][a][col], col = half*16+cc
    float* yb = &lds[pb*XS_PITCH + (half*16 + cc)];
    #pragma unroll
    for (int a = 0; a < 16; ++a) yb[a*36] = acc[a];
  }

  // ---- Phase C weights (after Phase B: r12 showed hoisting costs 60 VGPR -> occupancy collapse)
  const int ahC = tid >> 7, oC = (tid >> 2) & 31, cbC = tid & 3;
  v2f WC[4][9];
  {
    const float* wo = Wo + (size_t)(oC*32 + cbC*8)*9;
    #pragma unroll
    for (int cp = 0; cp < 4; ++cp)
      #pragma unroll
      for (int w = 0; w < 9; ++w)
        WC[cp][w] = (v2f){ wo[(2*cp)*9 + w], wo[(2*cp+1)*9 + w] };
  }
  __syncthreads();

  // ---- Phase C: equi_linear(y, W_out) -> out (unroll 2)
  #pragma unroll 2
  for (int p = 0; p < NP; ++p) {
    const float* yb = &lds[p*XS_PITCH + cbC*8];
    v2f acc[8];
    #pragma unroll
    for (int j = 0; j < 8; ++j) acc[j] = (v2f){0.f, 0.f};
    if (ahC == 0) equi2_half<0>(yb, WC, acc);
    else          equi2_half<4>(yb, WC, acc);
    float f[8];
    #pragma unroll
    for (int j = 0; j < 8; ++j) f[j] = xadd2(xadd1(acc[j].x + acc[j].y));
    float2 st;
    st.x = sel4(f[0], f[2], f[4], f[6], cbC);
    st.y = sel4(f[1], f[3], f[5], f[7], cbC);
    *(float2*)&out[(pos0 + p)*512 + oC*16 + ahC*8 + cbC*2] = st;
  }
}

extern "C" void kernel_launch(void* const* d_in, const int* in_sizes, int n_in,
                              void* d_out, int out_size, void* d_ws, size_t ws_size,
                              hipStream_t stream) {
  const float* x  = (const float*)d_in[0];
  const float* rm = (const float*)d_in[1];
  const float* wb = (const float*)d_in[2];
  const float* wo = (const float*)d_in[3];
  float* out = (float*)d_out;
  const int P = in_sizes[0] / 512;   // B*S positions
  const int blocks = P / NP;         // 8192 for the bench shape
  pga_fused<<<blocks, 256, 0, stream>>>(x, rm, wb, wo, out);
}